// Round 8
// baseline (25465.250 us; speedup 1.0000x reference)
//
#include <hip/hip_runtime.h>
#include <hip/hip_cooperative_groups.h>
#include <math.h>

typedef unsigned int u32x4 __attribute__((ext_vector_type(4)));

constexpr int T = 4096;   // SEQ_LEN
constexpr int R = 2048;   // RES_SIZE
constexpr int J = 128;    // INPUT_SIZE
constexpr float ONE_MINUS_LEAK = 0.1f;
constexpr float LEAK = 0.9f;
constexpr float INV_SQRT_R = 0.022097086912079608f;  // 1/sqrt(2048)

constexpr int NWG = 256;               // one WG per CU; 8 rows per WG
constexpr unsigned SENT = 0xFFFFFFFFu; // sentinel bits (-NaN; unreachable)

// ---------------- Kernel A: proj[t][r] = input[t] . W_in[r] + bias[r] -> d_out
__global__ __launch_bounds__(256) void esn_proj_kernel(
    const float* __restrict__ U, const float* __restrict__ Win,
    const float* __restrict__ bias, float* __restrict__ out)
{
    __shared__ float As[16][129];
    __shared__ float Bs[16][129];
    const int tb = blockIdx.x * 16;
    const int rb = blockIdx.y * 16;
    const int tid = threadIdx.x;

    for (int i = tid; i < 16 * J; i += 256) {
        int r = i >> 7, c = i & 127;
        As[r][c] = U[(size_t)(tb + r) * J + c];
        Bs[r][c] = Win[(size_t)(rb + r) * J + c];
    }
    __syncthreads();

    const int ti = tid >> 4;
    const int rj = tid & 15;
    float acc = 0.f;
#pragma unroll
    for (int k = 0; k < J; ++k) acc = fmaf(As[ti][k], Bs[rj][k], acc);
    out[(size_t)(tb + ti) * R + (rb + rj)] = acc + bias[rb + rj];
}

// ---------------- Kernel B: dataflow recurrence (no per-step __syncthreads)
// 256 WGs x 512 threads; wave v (of 8) owns row wg*8+v AND polls the global
// 1KB chunk x[256v .. 256v+255] of the R7-proven sentinel ring buf[4][R].
// Groups of 64 f32 are staged to LDS as they become fresh; LDS flags carry a
// MONOTONE tag (= step t, compared with >=), so a consumer that observes a
// later tag safely reads the still-live xs[t&1] copy (overwritten only at
// t+2, by which time every wave in this WG has published x^{t+1} -- skew<=1).
// Re-arm/publish ordering proof is R7's (ring slot (t+2)&3 differs from any
// slot polled by waves within skew 3; vmcnt(0) acks re-arm before publish).
__global__ __launch_bounds__(512, 2) void esn_recur_kernel(
    const float* __restrict__ Wres, float* __restrict__ out,
    unsigned* __restrict__ buf /* [4][R] */)
{
    const int wg   = blockIdx.x;
    const int tid  = threadIdx.x;
    const int wv   = tid >> 6;        // wave 0..7
    const int lane = tid & 63;
    const int row  = wg * 8 + wv;
    const int gsub = lane >> 4;       // group within my chunk (0..3)

    // Row weights in registers: lane holds w[k] for col k*64+lane.
    float w[32];
    {
        const float* wr = Wres + (size_t)row * R + lane;
#pragma unroll
        for (int k = 0; k < 32; ++k) w[k] = wr[k * 64];
    }

    __shared__ __align__(16) float xs[2][R];  // LDS copy, depth 2
    __shared__ int flags[32];                 // per-group monotone tag
    if (tid < 32) flags[tid] = -1;
    __syncthreads();                          // one-time init only

    float xold = 0.f;       // my row's previous state (lane 0)
    long guard = 0;         // converts protocol bugs into fast wrong answers

    for (int t = 0; t < T; ++t) {
        // Input projection prefetch (hides under the poll).
        float proj = (lane == 0) ? out[(size_t)t * R + row] : 0.f;

        // ---- Poll my 1KB chunk of ring slot (t&3); stage groups as fresh.
        const unsigned* p = buf + (size_t)(t & 3) * R + 256 * wv + 4 * lane;
        float* dst = xs[t & 1] + 256 * wv + 4 * lane;
        bool written = false;
        unsigned flagged = 0;                 // 4 bits, uniform across wave
        while (flagged != 0xFu) {
            if (++guard > 50000000L) break;
            u32x4 v;
            asm volatile(
                "global_load_dwordx4 %0, %1, off sc0 sc1\n\t"
                "s_waitcnt vmcnt(0)"
                : "=&v"(v) : "v"(p) : "memory");
            const bool fresh = v[0] != SENT && v[1] != SENT &&
                               v[2] != SENT && v[3] != SENT;
            if (fresh && !written) {          // predicated 16B LDS store
                *(u32x4*)dst = v;
                written = true;
            }
            const unsigned long long bal = __ballot(fresh);
            unsigned newly = 0;
#pragma unroll
            for (int g = 0; g < 4; ++g)
                if (!(flagged & (1u << g)) &&
                    ((bal >> (16 * g)) & 0xFFFFull) == 0xFFFFull)
                    newly |= 1u << g;
            if (newly) {
                // All ds_writes of the newly-complete groups precede this.
                asm volatile("s_waitcnt lgkmcnt(0)" ::: "memory");
                __builtin_amdgcn_sched_barrier(0);
                if ((newly & (1u << gsub)) && lane == gsub * 16)
                    __hip_atomic_store(&flags[wv * 4 + gsub], t,
                                       __ATOMIC_RELAXED,
                                       __HIP_MEMORY_SCOPE_WORKGROUP);
                flagged |= newly;
            }
        }

        // ---- Wait until ALL 32 groups are staged (tags monotone: >= t).
        while (true) {
            if (++guard > 50000000L) break;
            const int f = __hip_atomic_load(&flags[lane & 31],
                                            __ATOMIC_RELAXED,
                                            __HIP_MEMORY_SCOPE_WORKGROUP);
            if (__ballot(f >= t) == ~0ull) break;
        }
        __builtin_amdgcn_sched_barrier(0);

        // ---- Burst: 32 conflict-free LDS reads + 4 FMA chains.
        const float* x = xs[t & 1];
        float a0 = 0.f, a1 = 0.f, a2 = 0.f, a3 = 0.f;
#pragma unroll
        for (int k = 0; k < 8; ++k) {
            a0 = fmaf(w[4 * k + 0], x[(4 * k + 0) * 64 + lane], a0);
            a1 = fmaf(w[4 * k + 1], x[(4 * k + 1) * 64 + lane], a1);
            a2 = fmaf(w[4 * k + 2], x[(4 * k + 2) * 64 + lane], a2);
            a3 = fmaf(w[4 * k + 3], x[(4 * k + 3) * 64 + lane], a3);
        }
        float acc = (a0 + a1) + (a2 + a3);
#pragma unroll
        for (int off = 32; off > 0; off >>= 1)
            acc += __shfl_xor(acc, off);

        if (lane == 0) {
            // Re-arm ring (t+2)&3 for my row, ack, THEN publish (R7 proof).
            __hip_atomic_store(&buf[(size_t)((t + 2) & 3) * R + row], SENT,
                               __ATOMIC_RELAXED, __HIP_MEMORY_SCOPE_AGENT);
            asm volatile("s_waitcnt vmcnt(0)" ::: "memory");
            float pre  = acc + proj;          // RES_SCALE = INPUT_SCALE = 1
            float xnew = ONE_MINUS_LEAK * xold + LEAK * erff(pre) * INV_SQRT_R;
            xold = xnew;
            __hip_atomic_store(&buf[(size_t)((t + 1) & 3) * R + row],
                               __float_as_uint(xnew),
                               __ATOMIC_RELAXED, __HIP_MEMORY_SCOPE_AGENT);
            out[(size_t)t * R + row] = xnew;  // states output
        }
    }
}

extern "C" void kernel_launch(void* const* d_in, const int* in_sizes, int n_in,
                              void* d_out, int out_size, void* d_ws, size_t ws_size,
                              hipStream_t stream) {
    const float* U    = (const float*)d_in[0];  // (4096,128)
    const float* Win  = (const float*)d_in[1];  // (2048,128)
    const float* Wres = (const float*)d_in[2];  // (2048,2048)
    const float* bias = (const float*)d_in[3];  // (2048,)
    float* out = (float*)d_out;                 // (4096,2048)
    unsigned* buf = (unsigned*)d_ws;            // [4][R] u32 sentinel ring

    // Ring slot 0 = 0.0f everywhere (valid x^0); slots 1..3 = sentinel.
    hipMemsetAsync(buf, 0x00, (size_t)R * sizeof(unsigned), stream);
    hipMemsetAsync((char*)d_ws + (size_t)R * sizeof(unsigned), 0xFF,
                   (size_t)3 * R * sizeof(unsigned), stream);

    dim3 pgrid(T / 16, R / 16);
    esn_proj_kernel<<<pgrid, dim3(256), 0, stream>>>(U, Win, bias, out);

    void* args[] = { (void*)&Wres, (void*)&out, (void*)&buf };
    hipLaunchCooperativeKernel((const void*)esn_recur_kernel,
                               dim3(NWG), dim3(512), args, 0, stream);
}

// Round 9
// 19293.793 us; speedup vs baseline: 1.3199x; 1.3199x over previous
//
#include <hip/hip_runtime.h>
#include <hip/hip_cooperative_groups.h>
#include <math.h>

typedef unsigned int u32x4 __attribute__((ext_vector_type(4)));
typedef unsigned long long ull;

constexpr int T = 4096;   // SEQ_LEN
constexpr int R = 2048;   // RES_SIZE
constexpr int J = 128;    // INPUT_SIZE
constexpr float ONE_MINUS_LEAK = 0.1f;
constexpr float LEAK = 0.9f;
constexpr float INV_SQRT_R = 0.022097086912079608f;  // 1/sqrt(2048)

constexpr int NWG  = 256;  // one WG per CU (forced by LDS)
constexpr int NREP = 4;    // slot replicas

// ---------------- Kernel A: proj[t][r] = input[t] . W_in[r] + bias[r] -> d_out
__global__ __launch_bounds__(256) void esn_proj_kernel(
    const float* __restrict__ U, const float* __restrict__ Win,
    const float* __restrict__ bias, float* __restrict__ out)
{
    __shared__ float As[16][129];
    __shared__ float Bs[16][129];
    const int tb = blockIdx.x * 16;
    const int rb = blockIdx.y * 16;
    const int tid = threadIdx.x;

    for (int i = tid; i < 16 * J; i += 256) {
        int r = i >> 7, c = i & 127;
        As[r][c] = U[(size_t)(tb + r) * J + c];
        Bs[r][c] = Win[(size_t)(rb + r) * J + c];
    }
    __syncthreads();

    const int ti = tid >> 4;
    const int rj = tid & 15;
    float acc = 0.f;
#pragma unroll
    for (int k = 0; k < J; ++k) acc = fmaf(As[ti][k], Bs[rj][k], acc);
    out[(size_t)(tb + ti) * R + (rb + rj)] = acc + bias[rb + rj];
}

// Poll 4 consecutive 1KB-strided dwordx4 from one base (offsets fit 13-bit).
#define POLL4(vv0, vv1, vv2, vv3, pp)                                   \
    asm volatile(                                                       \
        "global_load_dwordx4 %0, %4, off sc0 sc1\n\t"                   \
        "global_load_dwordx4 %1, %4, off offset:1024 sc0 sc1\n\t"       \
        "global_load_dwordx4 %2, %4, off offset:2048 sc0 sc1\n\t"       \
        "global_load_dwordx4 %3, %4, off offset:3072 sc0 sc1"           \
        : "=&v"(vv0), "=&v"(vv1), "=&v"(vv2), "=&v"(vv3)                \
        : "v"(pp) : "memory")

// ---------------- Kernel B: persistent recurrence, single-poller-per-WG
// 256 WGs x 512 threads; wave v owns row wg*8+v. slots[2][NREP][R] ull:
// lo32 = f32 bits, hi32 = tag (step index). Publish = one 8B agent store
// per replica (R4/R5-proven). ONLY wave 0 polls (16 dwordx4/lane in one
// RTT covers 16KB); it stages to LDS and releases an LDS `go` word that
// waves 1..7 acquire -- 8x lower grid poll rate, zero extra global hops.
// Skew<=1 induction identical to R4 (detect(t) completes before any
// producer can publish tag t+2 into the same slot line).
__global__ __launch_bounds__(512) void esn_recur_kernel(
    const float* __restrict__ Wres, float* __restrict__ out,
    ull* __restrict__ slots /* [2][NREP][R] */)
{
    extern __shared__ char dyn_pad[];  // occupancy pad: forces 1 WG/CU
    (void)dyn_pad;

    const int wg   = blockIdx.x;
    const int tid  = threadIdx.x;
    const int wv   = tid >> 6;
    const int lane = tid & 63;
    const int row  = wg * 8 + wv;
    const int rep  = wg & (NREP - 1);

    // Row weights in registers (coalesced: 64 lanes x f32 per k)
    float w[32];
    {
        const float* wr = Wres + (size_t)row * R + lane;
#pragma unroll
        for (int k = 0; k < 32; ++k) w[k] = wr[k * 64];
    }

    __shared__ __align__(16) float xs[2][R];
    __shared__ int go;
    if (tid == 0) go = -1;
    __syncthreads();                      // one-time init only

    float xold = 0.f;                     // this row's previous state
    long  guard = 0;

    for (int t = 0; t < T; ++t) {
        // Input projection prefetch (latency hides under poll/spin).
        float proj = (lane == 0) ? out[(size_t)t * R + row] : 0.f;

        if (wv == 0) {
            // ---- Sole poller: sweep the whole 16KB replica in one RTT.
            const ull* base = slots + ((size_t)((t & 1) * NREP + rep)) * R;
            const ull* pb0 = base + 2 * lane;          // blk 0: slots +0
            const ull* pb1 = pb0 + 512;                // blk 1
            const ull* pb2 = pb0 + 1024;               // blk 2
            const ull* pb3 = pb0 + 1536;               // blk 3
            const unsigned want = (unsigned)t;
            u32x4 v[16];
            while (true) {
                POLL4(v[0],  v[1],  v[2],  v[3],  pb0);
                POLL4(v[4],  v[5],  v[6],  v[7],  pb1);
                POLL4(v[8],  v[9],  v[10], v[11], pb2);
                POLL4(v[12], v[13], v[14], v[15], pb3);
                asm volatile("s_waitcnt vmcnt(0)" ::: "memory");
                bool ok = true;
#pragma unroll
                for (int i = 0; i < 16; ++i)
                    ok &= (v[i][1] == want) & (v[i][3] == want);
                if (__all(ok)) break;
                if (++guard > (1L << 26)) break;   // bug -> fast wrong answer
            }
            // Stage 32 f32/lane to LDS (8B/lane stride: 2-way alias, free).
            float* xb = xs[t & 1];
#pragma unroll
            for (int i = 0; i < 16; ++i) {
                float2 f = make_float2(__uint_as_float(v[i][0]),
                                       __uint_as_float(v[i][2]));
                *(float2*)&xb[(i >> 2) * 512 + (i & 3) * 128 + 2 * lane] = f;
            }
            __hip_atomic_store(&go, t, __ATOMIC_RELEASE,
                               __HIP_MEMORY_SCOPE_WORKGROUP);
        } else {
            // ---- Wait for the poller (LDS-only spin; tags monotone).
            while (__hip_atomic_load(&go, __ATOMIC_ACQUIRE,
                                     __HIP_MEMORY_SCOPE_WORKGROUP) < t)
                if (++guard > (1L << 28)) break;
        }
        __builtin_amdgcn_sched_barrier(0);

        // ---- Row dot product: 32 conflict-free LDS reads, 4 FMA chains.
        const float* x = xs[t & 1];
        float a0 = 0.f, a1 = 0.f, a2 = 0.f, a3 = 0.f;
#pragma unroll
        for (int k = 0; k < 8; ++k) {
            a0 = fmaf(w[4 * k + 0], x[(4 * k + 0) * 64 + lane], a0);
            a1 = fmaf(w[4 * k + 1], x[(4 * k + 1) * 64 + lane], a1);
            a2 = fmaf(w[4 * k + 2], x[(4 * k + 2) * 64 + lane], a2);
            a3 = fmaf(w[4 * k + 3], x[(4 * k + 3) * 64 + lane], a3);
        }
        float acc = (a0 + a1) + (a2 + a3);
#pragma unroll
        for (int off = 32; off > 0; off >>= 1)
            acc += __shfl_xor(acc, off);

        if (lane == 0) {
            float pre  = acc + proj;          // RES_SCALE = INPUT_SCALE = 1
            float xnew = ONE_MINUS_LEAK * xold + LEAK * erff(pre) * INV_SQRT_R;
            xold = xnew;
            // Publish FIRST (critical path): one 8B store per replica.
            ull packed = ((ull)(unsigned)(t + 1) << 32) |
                         (ull)__float_as_uint(xnew);
            const size_t pb = (size_t)(((t + 1) & 1) * NREP) * R + row;
#pragma unroll
            for (int g = 0; g < NREP; ++g)
                __hip_atomic_store(&slots[pb + (size_t)g * R], packed,
                                   __ATOMIC_RELAXED, __HIP_MEMORY_SCOPE_AGENT);
            out[(size_t)t * R + row] = xnew;  // states output
        }
    }
}

extern "C" void kernel_launch(void* const* d_in, const int* in_sizes, int n_in,
                              void* d_out, int out_size, void* d_ws, size_t ws_size,
                              hipStream_t stream) {
    const float* U    = (const float*)d_in[0];  // (4096,128)
    const float* Win  = (const float*)d_in[1];  // (2048,128)
    const float* Wres = (const float*)d_in[2];  // (2048,2048)
    const float* bias = (const float*)d_in[3];  // (2048,)
    float* out = (float*)d_out;                 // (4096,2048)
    ull* slots = (ull*)d_ws;                    // [2][NREP][R]

    // tag0/value0 everywhere == valid x^0 = 0 in buf[0]; graph-replay safe.
    hipMemsetAsync(slots, 0, (size_t)2 * NREP * R * sizeof(ull), stream);

    dim3 pgrid(T / 16, R / 16);
    esn_proj_kernel<<<pgrid, dim3(256), 0, stream>>>(U, Win, bias, out);

    // 72 KB dynamic + 16.4 KB static LDS -> exactly 1 WG per CU.
    void* args[] = { (void*)&Wres, (void*)&out, (void*)&slots };
    hipLaunchCooperativeKernel((const void*)esn_recur_kernel,
                               dim3(NWG), dim3(512), args, 72 * 1024, stream);
}

// Round 11
// 11387.685 us; speedup vs baseline: 2.2362x; 1.6943x over previous
//
#include <hip/hip_runtime.h>
#include <hip/hip_cooperative_groups.h>
#include <math.h>

typedef unsigned int u32x4 __attribute__((ext_vector_type(4)));
typedef unsigned long long ull;

constexpr int T = 4096;   // SEQ_LEN
constexpr int R = 2048;   // RES_SIZE
constexpr int J = 128;    // INPUT_SIZE
constexpr float ONE_MINUS_LEAK = 0.1f;
constexpr float LEAK = 0.9f;
constexpr float INV_SQRT_R = 0.022097086912079608f;  // 1/sqrt(2048)

constexpr int NWG  = 64;   // rendezvous participants (was 256) -- the variable
constexpr int NREP = 2;    // keeps sharers-per-slot-line at R5's 32

// ---------------- Kernel A: proj[t][r] = input[t] . W_in[r] + bias[r] -> d_out
__global__ __launch_bounds__(256) void esn_proj_kernel(
    const float* __restrict__ U, const float* __restrict__ Win,
    const float* __restrict__ bias, float* __restrict__ out)
{
    __shared__ float As[16][129];
    __shared__ float Bs[16][129];
    const int tb = blockIdx.x * 16;
    const int rb = blockIdx.y * 16;
    const int tid = threadIdx.x;

    for (int i = tid; i < 16 * J; i += 256) {
        int r = i >> 7, c = i & 127;
        As[r][c] = U[(size_t)(tb + r) * J + c];
        Bs[r][c] = Win[(size_t)(rb + r) * J + c];
    }
    __syncthreads();

    const int ti = tid >> 4;
    const int rj = tid & 15;
    float acc = 0.f;
#pragma unroll
    for (int k = 0; k < J; ++k) acc = fmaf(As[ti][k], Bs[rj][k], acc);
    out[(size_t)(tb + ti) * R + (rb + rj)] = acc + bias[rb + rj];
}

// ---------------- Kernel B: R5's proven protocol at 64 participants.
// 64 WGs x 512 threads; WG w owns rows [32w, 32w+32); wave v owns 4 rows
// rowbase = 32w+4v .. +4. slots[2][NREP][R] ull: lo32 = f32 bits, hi32 = tag
// (step index of the state). Publish = one 8B sc0sc1 store per replica from
// lanes 0..3 (4 consecutive rows -> coalesced). Each WG polls replica (w&1):
// thread owns slots {2tid,2tid+1} and {1024+2tid,+1} -- verbatim R5 poll.
// Skew<=1 tag induction identical to R4/R5 (publish of tag t+1 into buffer
// (t+1)&1 only after this WG's poll(t) completed; any consumer still reading
// that buffer would contradict all-tags-t having been observed).
__global__ __launch_bounds__(512) void esn_recur_kernel(
    const float* __restrict__ Wres, float* __restrict__ out,
    ull* __restrict__ slots /* [2][NREP][R] */)
{
    const int wg   = blockIdx.x;
    const int tid  = threadIdx.x;
    const int wv   = tid >> 6;
    const int lane = tid & 63;
    const int rowbase = wg * 32 + wv * 4;   // this wave's 4 rows
    const int rep  = wg & (NREP - 1);

    // 4 rows of weights in registers (coalesced: 64 lanes x f32 per k).
    float w[4][32];
#pragma unroll
    for (int j = 0; j < 4; ++j) {
        const float* wr = Wres + (size_t)(rowbase + j) * R + lane;
#pragma unroll
        for (int k = 0; k < 32; ++k) w[j][k] = wr[k * 64];
    }

    __shared__ __align__(16) float xs[2][R];
    float xold = 0.f;    // lanes 0..3: previous state of row rowbase+lane
    long  spin = 0;      // cumulative guard: bugs -> fast wrong answer

    for (int t = 0; t < T; ++t) {
        // Input projection prefetch (latency hides under the poll).
        float proj = (lane < 4) ? out[(size_t)t * R + rowbase + lane] : 0.f;

        // ---- Poll x^{(t)} in our replica (R5-verbatim shape).
        const ull* src = slots + ((size_t)((t & 1) * NREP + rep)) * R;
        const ull* p0 = src + 2 * tid;
        const ull* p1 = src + 1024 + 2 * tid;
        const unsigned want = (unsigned)t;
        u32x4 v0, v1;
        while (true) {
            asm volatile(
                "global_load_dwordx4 %0, %2, off sc0 sc1\n\t"
                "global_load_dwordx4 %1, %3, off sc0 sc1\n\t"
                "s_waitcnt vmcnt(0)"
                : "=&v"(v0), "=&v"(v1)
                : "v"(p0), "v"(p1)
                : "memory");
            if (v0[1] == want && v0[3] == want &&
                v1[1] == want && v1[3] == want) break;
            if (++spin > (1L << 26)) break;
        }
        float* xb = xs[t & 1];
        xb[2 * tid]        = __uint_as_float(v0[0]);
        xb[2 * tid + 1]    = __uint_as_float(v0[2]);
        xb[2 * tid + 1024] = __uint_as_float(v1[0]);
        xb[2 * tid + 1025] = __uint_as_float(v1[2]);
        __syncthreads();   // the only barrier per step: stage -> dot join

        // ---- x into registers once (2-way LDS alias: free), reuse 4 rows.
        const float* x = xs[t & 1];
        float xr[32];
#pragma unroll
        for (int k = 0; k < 32; ++k) xr[k] = x[k * 64 + lane];

        float mysum = 0.f;
#pragma unroll
        for (int j = 0; j < 4; ++j) {
            float a0 = 0.f, a1 = 0.f, a2 = 0.f, a3 = 0.f;
#pragma unroll
            for (int k = 0; k < 8; ++k) {
                a0 = fmaf(w[j][4 * k + 0], xr[4 * k + 0], a0);
                a1 = fmaf(w[j][4 * k + 1], xr[4 * k + 1], a1);
                a2 = fmaf(w[j][4 * k + 2], xr[4 * k + 2], a2);
                a3 = fmaf(w[j][4 * k + 3], xr[4 * k + 3], a3);
            }
            float acc = (a0 + a1) + (a2 + a3);
#pragma unroll
            for (int off = 32; off > 0; off >>= 1)
                acc += __shfl_xor(acc, off);
            if (lane == j) mysum = acc;          // static j -> cndmask
        }

        // ---- Lanes 0..3 finalize their row, publish, write output.
        if (lane < 4) {
            const float pre  = mysum + proj;     // proj includes bias
            const float xnew = ONE_MINUS_LEAK * xold +
                               LEAK * erff(pre) * INV_SQRT_R;
            xold = xnew;
            const ull packed = ((ull)(unsigned)(t + 1) << 32) |
                               (ull)__float_as_uint(xnew);
            const size_t pb = (size_t)(((t + 1) & 1) * NREP) * R
                            + rowbase + lane;
#pragma unroll
            for (int g = 0; g < NREP; ++g)
                __hip_atomic_store(&slots[pb + (size_t)g * R], packed,
                                   __ATOMIC_RELAXED, __HIP_MEMORY_SCOPE_AGENT);
            out[(size_t)t * R + rowbase + lane] = xnew;  // states output
        }
    }
}

extern "C" void kernel_launch(void* const* d_in, const int* in_sizes, int n_in,
                              void* d_out, int out_size, void* d_ws, size_t ws_size,
                              hipStream_t stream) {
    const float* U    = (const float*)d_in[0];  // (4096,128)
    const float* Win  = (const float*)d_in[1];  // (2048,128)
    const float* Wres = (const float*)d_in[2];  // (2048,2048)
    const float* bias = (const float*)d_in[3];  // (2048,)
    float* out = (float*)d_out;                 // (4096,2048)
    ull* slots = (ull*)d_ws;                    // [2][NREP][R]

    // tag0/value0 everywhere == valid x^0 = 0 in buf[0]; graph-replay safe.
    hipMemsetAsync(slots, 0, (size_t)2 * NREP * R * sizeof(ull), stream);

    dim3 pgrid(T / 16, R / 16);
    esn_proj_kernel<<<pgrid, dim3(256), 0, stream>>>(U, Win, bias, out);

    void* args[] = { (void*)&Wres, (void*)&out, (void*)&slots };
    hipLaunchCooperativeKernel((const void*)esn_recur_kernel,
                               dim3(NWG), dim3(512), args, 0, stream);
}